// Round 12
// baseline (864.574 us; speedup 1.0000x reference)
//
#include <hip/hip_runtime.h>

#define D_FEAT 64
#define NBLK 256
#define NTHR 1024
#define GRIDTHR (NBLK * NTHR)

// tiny pre-kernel: zero the grid-barrier counter (ws is poisoned every call)
__global__ void zero_bar_kernel(int* bar) {
    if (threadIdx.x < 4) bar[threadIdx.x] = 0;
}

// Grid barrier v2 (R10 post-mortem fix): poll with RELAXED loads + s_sleep
// backoff so waiting blocks don't flood the fabric/LLC while straggler blocks
// are still working (R10's acquire-poll storm = 200us/barrier). Release is the
// __threadfence before the add; acquire is the __threadfence after exit.
// Safe: 256 blocks x 1024thr x 32KB LDS = 1 block/CU guaranteed co-resident.
__device__ inline void grid_barrier(int* bar, int target) {
    __threadfence();
    __syncthreads();
    if (threadIdx.x == 0) {
        __hip_atomic_fetch_add(bar, 1, __ATOMIC_ACQ_REL, __HIP_MEMORY_SCOPE_AGENT);
        while (__hip_atomic_load(bar, __ATOMIC_RELAXED, __HIP_MEMORY_SCOPE_AGENT) < target)
            __builtin_amdgcn_s_sleep(8);
    }
    __syncthreads();
    __threadfence();
}

__global__ __launch_bounds__(NTHR, 4) void mega_kernel(
    const float* __restrict__ feat, const int* __restrict__ src,
    const int* __restrict__ dst, float* __restrict__ out,
    int* bar, unsigned* packed_src, int* deg_dst, int* agg, int* incl,
    unsigned* packed, unsigned short* rank, int4* edges4,
    int N, int E, int zeroA_i4)
{
    __shared__ unsigned int shmem[8192];   // 32KB: P1b hist / P2 scan overlay
    __shared__ int s_prev;
    const int t = threadIdx.x;
    const int b = blockIdx.x;
    const int tid = b * NTHR + t;

    // ---------- P0: zero counter region + out ----------
    {
        int4* pA = (int4*)packed_src;              // counters (16B-aligned)
        int4* pO = (int4*)out;
        const int nO4 = (N * D_FEAT) / 4;
        const int4 z4 = make_int4(0, 0, 0, 0);
        for (int i = tid; i < zeroA_i4; i += GRIDTHR) pA[i] = z4;
        for (int i = tid; i < nO4; i += GRIDTHR) pO[i] = z4;
    }
    grid_barrier(bar, NBLK);

    // ---------- P1a: dst histogram + rank (random return-atomics) ----------
    {
        int e4 = tid * 4;
        if (e4 + 3 < E) {
            int4 d4 = *(const int4*)(dst + e4);
            ushort4 r;
            r.x = (unsigned short)atomicAdd(&deg_dst[d4.x], 1);
            r.y = (unsigned short)atomicAdd(&deg_dst[d4.y], 1);
            r.z = (unsigned short)atomicAdd(&deg_dst[d4.z], 1);
            r.w = (unsigned short)atomicAdd(&deg_dst[d4.w], 1);
            *(ushort4*)(rank + e4) = r;
        } else {
            for (int e = e4; e < E; ++e)
                rank[e] = (unsigned short)atomicAdd(&deg_dst[dst[e]], 1);
        }
    }
    // ---------- P1b: src histogram, LDS-privatized (no barrier before: ----
    // independent arrays; early P1a finishers overlap into P1b naturally) ----
    if (b < 252) {                           // 7 ranges x 36 chunks
        const int range = b % 7;
        const int chunk = b / 7;
        const int lo = range << 14;          // 16384 nodes/range
        __syncthreads();
        for (int i = t; i < 8192; i += NTHR) shmem[i] = 0;
        __syncthreads();
        const int cs = (E + 35) / 36;
        const int e0 = chunk * cs, e1 = min(e0 + cs, E);
        for (int e = e0 + t; e < e1; e += NTHR) {
            unsigned r = (unsigned)(src[e] - lo);
            if (r < 16384u) atomicAdd(&shmem[r >> 1], 1u << ((r & 1) << 4));
        }
        __syncthreads();
        for (int i = t; i < 8192; i += NTHR) {
            unsigned v = shmem[i];
            if (v) atomicAdd(&packed_src[(lo >> 1) + i], v);   // coalesced
        }
    }
    grid_barrier(bar, 2 * NBLK);

    // ---------- P2: decoupled-lookback scan -> packed (rs<<12 | deg) ----------
    {
        int* lds = (int*)shmem;
        const int nchunk = (N + NTHR - 1) / NTHR;   // 98
        if (b < nchunk) {
            const int i = b * NTHR + t;
            int v = (i < N) ? deg_dst[i] : 0;
            lds[t] = v;
            __syncthreads();
            for (int off = 1; off < NTHR; off <<= 1) {
                int x = (t >= off) ? lds[t - off] : 0;
                __syncthreads();
                lds[t] += x;
                __syncthreads();
            }
            const int local_incl = lds[t];
            const int total = lds[NTHR - 1];
            if (t == 0)
                __hip_atomic_store(&agg[b], total + 1, __ATOMIC_RELEASE,
                                   __HIP_MEMORY_SCOPE_AGENT);
            if (t < 64) {
                int prev = 0;
                if (b > 0) {
                    int j = b - 1;
                    while (true) {
                        int idx = j - t;
                        bool valid = (idx >= 0);
                        int iv = 0, av = 0;
                        if (valid) {
                            while (true) {
                                iv = __hip_atomic_load(&incl[idx], __ATOMIC_ACQUIRE,
                                                       __HIP_MEMORY_SCOPE_AGENT);
                                if (iv) break;
                                if (idx > 0) {   // idx==0: inclusive only (R5 fix)
                                    av = __hip_atomic_load(&agg[idx], __ATOMIC_ACQUIRE,
                                                           __HIP_MEMORY_SCOPE_AGENT);
                                    if (av) break;
                                }
                            }
                        }
                        unsigned long long m = __ballot(valid && (iv != 0));
                        int contrib; bool done;
                        if (m) {
                            int lstar = __ffsll((long long)m) - 1;
                            contrib = (t < lstar) ? (av - 1) : (t == lstar ? iv - 1 : 0);
                            done = true;
                        } else {
                            contrib = valid ? (av - 1) : 0;
                            done = false;
                        }
                        #pragma unroll
                        for (int off = 32; off >= 1; off >>= 1)
                            contrib += __shfl_xor(contrib, off);
                        prev += contrib;
                        if (done) break;
                        j -= 64;
                    }
                }
                if (t == 0) {
                    __hip_atomic_store(&incl[b], prev + total + 1, __ATOMIC_RELEASE,
                                       __HIP_MEMORY_SCOPE_AGENT);
                    s_prev = prev;
                }
            }
            __syncthreads();
            if (i < N) {
                unsigned rs = (unsigned)(s_prev + local_incl - v);
                packed[i] = (rs << 12) | (unsigned)min(v, 4095);
            }
        }
    }
    grid_barrier(bar, 3 * NBLK);

    // ---------- P3: place (both norms folded into edge coef) ----------
    for (int e = tid; e < E; e += GRIDTHR) {
        int s = src[e], d = dst[e];
        unsigned pv = packed[d];
        int pos  = (int)(pv >> 12) + (int)rank[e];
        int degd = (int)(pv & 4095u);
        unsigned sp = packed_src[s >> 1];
        int degs = (int)((sp >> ((s & 1) << 4)) & 0xffffu);
        float coef = rsqrtf((float)max(degs, 1)) * rsqrtf((float)max(degd, 1));
        edges4[pos] = make_int4(s, __float_as_int(coef), d, 0);
    }
    grid_barrier(bar, 4 * NBLK);

    // ---------- P4: edge-parallel segmented aggregate (R10-verified) ----------
    {
        const int lane = t & 63;
        const int g = lane >> 4, q = lane & 15;
        const int waveid = b * (NTHR / 64) + (t >> 6);
        const int nwin = (E + 63) >> 6;
        for (int win = waveid; win < nwin; win += NBLK * (NTHR / 64)) {
            int e = (win << 6) + lane;
            int4 ed = (e < E) ? edges4[e] : make_int4(0, 0, -1, 0);
            int   d_l = ed.z, s_l = ed.x;
            float c_l = __int_as_float(ed.y);
            int d_prev = __shfl_up(d_l, 1);
            bool newrun = (lane == 0) || (d_l != d_prev);
            unsigned long long bmask = __ballot(newrun);
            int a = 0;
            while (a < 64) {
                unsigned long long rest =
                    (a < 63) ? ((bmask >> (a + 1)) << (a + 1)) : 0ull;
                int bb = rest ? (int)__builtin_ctzll(rest) : 64;
                int dcur = __shfl(d_l, a);
                if (dcur >= 0) {
                    float4 acc = make_float4(0.f, 0.f, 0.f, 0.f);
                    int n4 = (bb - a + 3) >> 2;
                    for (int t4 = 0; t4 < n4; ++t4) {
                        int p = a + t4 * 4 + g;
                        int   sj = __shfl(s_l, p & 63);
                        float cj = __shfl(c_l, p & 63);
                        if (p >= bb) cj = 0.f;   // inactive slot: row load harmless
                        const float4 row =
                            *(const float4*)(feat + (size_t)sj * D_FEAT + (q << 2));
                        acc.x += row.x * cj; acc.y += row.y * cj;
                        acc.z += row.z * cj; acc.w += row.w * cj;
                    }
                    #pragma unroll
                    for (int m = 16; m <= 32; m <<= 1) {
                        acc.x += __shfl_xor(acc.x, m); acc.y += __shfl_xor(acc.y, m);
                        acc.z += __shfl_xor(acc.z, m); acc.w += __shfl_xor(acc.w, m);
                    }
                    bool bnd = (a == 0) || (bb == 64);   // may continue in adj window
                    if (g == 0) {
                        float* o = out + (size_t)dcur * D_FEAT + (q << 2);
                        if (bnd) {
                            atomicAdd(o + 0, acc.x); atomicAdd(o + 1, acc.y);
                            atomicAdd(o + 2, acc.z); atomicAdd(o + 3, acc.w);
                        } else {
                            *(float4*)o = acc;
                        }
                    }
                }
                a = bb;
            }
        }
    }
}

extern "C" void kernel_launch(void* const* d_in, const int* in_sizes, int n_in,
                              void* d_out, int out_size, void* d_ws, size_t ws_size,
                              hipStream_t stream) {
    const float* feat = (const float*)d_in[0];
    const int*   src  = (const int*)d_in[1];
    const int*   dst  = (const int*)d_in[2];
    float* out = (float*)d_out;

    const int E = in_sizes[1];
    const int N = in_sizes[0] / D_FEAT;

    // ws layout (ints): bar(16) | packed_src(65536) deg_dst(N) agg(128) incl(128)
    //                   | packed(N) rank(E u16) | edges4(E int4, 16B-aligned)
    int* bar = (int*)d_ws;
    unsigned* packed_src = (unsigned*)(bar + 16);
    int* deg_dst = (int*)(packed_src + 65536);
    int* agg  = deg_dst + N;
    int* incl = agg + 128;
    unsigned* packed = (unsigned*)(incl + 128);
    unsigned short* rank = (unsigned short*)(packed + N);
    size_t off_ints = 16 + 65536 + (size_t)N + 256 + (size_t)N + (size_t)(E + 1) / 2;
    off_ints = (off_ints + 3) & ~(size_t)3;          // 16B align
    int4* edges4 = (int4*)((int*)d_ws + off_ints);
    (void)ws_size;

    const int zeroA_ints = 65536 + N + 256;          // packed_src..incl
    const int zeroA_i4   = (zeroA_ints + 3) / 4;     // <=3-int overrun lands in
                                                     // packed[] (rewritten in P2)

    zero_bar_kernel<<<1, 64, 0, stream>>>(bar);
    mega_kernel<<<NBLK, NTHR, 0, stream>>>(feat, src, dst, out,
                                           bar, packed_src, deg_dst, agg, incl,
                                           packed, rank, edges4,
                                           N, E, zeroA_i4);
}

// Round 13
// 213.468 us; speedup vs baseline: 4.0501x; 4.0501x over previous
//
#include <hip/hip_runtime.h>

#define D_FEAT 64
#define HIST_RANGES 4              // 4 x 32768 nodes (64KB LDS tile)
#define HIST_CHUNKS 48
#define SCAN_THR 1024

// ---------------- zero-fill: counter region + out ----------------------------
// (rocclr fillBuffer measured 43us for 663KB — do it ourselves)
__global__ void zero_kernel(int4* __restrict__ a, int na4,
                            int4* __restrict__ b, int nb4) {
    int i = blockIdx.x * blockDim.x + threadIdx.x;
    const int4 z = make_int4(0, 0, 0, 0);
    if (i < na4) a[i] = z;
    else if (i < na4 + nb4) b[i - na4] = z;
}

// ---------------- dst histogram + rank (counting-sort key) -------------------
// Random return-atomics at the ~830 GB/s 32B-sector RMW roofline (R9).
// Do NOT fuse with LDS-heavy roles (R8/R11: occupancy loss kills it).
__global__ void dst_rank_kernel(const int* __restrict__ dst, int* __restrict__ deg_dst,
                                unsigned short* __restrict__ rank, int E) {
    int e4 = (blockIdx.x * blockDim.x + threadIdx.x) * 4;
    if (e4 + 3 < E) {
        int4 d = *(const int4*)(dst + e4);
        ushort4 r;
        r.x = (unsigned short)atomicAdd(&deg_dst[d.x], 1);
        r.y = (unsigned short)atomicAdd(&deg_dst[d.y], 1);
        r.z = (unsigned short)atomicAdd(&deg_dst[d.z], 1);
        r.w = (unsigned short)atomicAdd(&deg_dst[d.w], 1);
        *(ushort4*)(rank + e4) = r;            // coalesced 8B store
    } else {
        for (int e = e4; e < E; ++e)
            rank[e] = (unsigned short)atomicAdd(&deg_dst[dst[e]], 1);
    }
}

// ---------------- merged: decoupled-lookback scan || src LDS histogram -------
// Blocks [0, nscan): exclusive scan of deg_dst -> packed (rs<<12 | deg).
// Blocks [nscan, nscan + 4*48): src histogram (range x chunk), coalesced merge.
// Unlike the R8/R11 fusion failure, NEITHER role is atomic-latency-bound:
// 64KB LDS still allows 2 blocks/CU -> all 290 blocks co-resident (lookback
// safe), and both roles are short. Saves a launch + overlaps the hist.
__global__ void scan_hist_kernel(const int* __restrict__ deg,
                                 unsigned* __restrict__ packed_rs,
                                 int* __restrict__ agg, int* __restrict__ incl,
                                 const int* __restrict__ src,
                                 unsigned* __restrict__ packed_src,
                                 int N, int E, int nscan) {
    __shared__ unsigned shmem[16384];          // 64KB; scan overlays first 4KB
    const int t = threadIdx.x;
    const int b = blockIdx.x;
    if (b < nscan) {
        int* lds = (int*)shmem;
        __shared__ int s_prev;
        const int i = b * SCAN_THR + t;
        int v = (i < N) ? deg[i] : 0;
        lds[t] = v;
        __syncthreads();
        for (int off = 1; off < SCAN_THR; off <<= 1) {
            int x = (t >= off) ? lds[t - off] : 0;
            __syncthreads();
            lds[t] += x;
            __syncthreads();
        }
        const int local_incl = lds[t];
        const int total = lds[SCAN_THR - 1];
        if (t == 0)
            __hip_atomic_store(&agg[b], total + 1, __ATOMIC_RELEASE,
                               __HIP_MEMORY_SCOPE_AGENT);
        if (t < 64) {
            int prev = 0;
            if (b > 0) {
                int j = b - 1;
                while (true) {
                    int idx = j - t;
                    bool valid = (idx >= 0);
                    int iv = 0, av = 0;
                    if (valid) {
                        while (true) {
                            iv = __hip_atomic_load(&incl[idx], __ATOMIC_ACQUIRE,
                                                   __HIP_MEMORY_SCOPE_AGENT);
                            if (iv) break;
                            if (idx > 0) {     // idx==0: inclusive only (R5 fix)
                                av = __hip_atomic_load(&agg[idx], __ATOMIC_ACQUIRE,
                                                       __HIP_MEMORY_SCOPE_AGENT);
                                if (av) break;
                            }
                        }
                    }
                    unsigned long long m = __ballot(valid && (iv != 0));
                    int contrib; bool done;
                    if (m) {
                        int lstar = __ffsll((long long)m) - 1;
                        contrib = (t < lstar) ? (av - 1) : (t == lstar ? iv - 1 : 0);
                        done = true;
                    } else {
                        contrib = valid ? (av - 1) : 0;
                        done = false;
                    }
                    #pragma unroll
                    for (int off = 32; off >= 1; off >>= 1)
                        contrib += __shfl_xor(contrib, off);
                    prev += contrib;
                    if (done) break;
                    j -= 64;
                }
            }
            if (t == 0) {
                __hip_atomic_store(&incl[b], prev + total + 1, __ATOMIC_RELEASE,
                                   __HIP_MEMORY_SCOPE_AGENT);
                s_prev = prev;
            }
        }
        __syncthreads();
        if (i < N) {
            unsigned rs = (unsigned)(s_prev + local_incl - v);
            packed_rs[i] = (rs << 12) | (unsigned)min(v, 4095);
        }
    } else {
        const int id    = b - nscan;
        const int range = id & (HIST_RANGES - 1);
        const int chunk = id >> 2;
        const int lo    = range << 15;         // 32768 nodes per range
        for (int i = t; i < 16384; i += SCAN_THR) shmem[i] = 0;
        __syncthreads();
        const int cs = (E + HIST_CHUNKS - 1) / HIST_CHUNKS;
        const int e0 = chunk * cs, e1 = min(e0 + cs, E);
        for (int e = e0 + t; e < e1; e += SCAN_THR) {
            unsigned r = (unsigned)(src[e] - lo);
            if (r < 32768u) atomicAdd(&shmem[r >> 1], 1u << ((r & 1) << 4));
        }
        __syncthreads();
        for (int i = t; i < 16384; i += SCAN_THR) {
            unsigned v = shmem[i];
            if (v) atomicAdd(&packed_src[(lo >> 1) + i], v);  // coalesced, skip-zero
        }
    }
}

// ---------------- place: no atomics, both norms folded into the coef ---------
__global__ void place_kernel(const int* __restrict__ src, const int* __restrict__ dst,
                             const unsigned short* __restrict__ rank,
                             const unsigned* __restrict__ packed_rs,
                             const unsigned* __restrict__ packed_src,
                             int4* __restrict__ edges4, int E) {
    int e = blockIdx.x * blockDim.x + threadIdx.x;
    if (e >= E) return;
    int s = src[e], d = dst[e];
    unsigned pv = packed_rs[d];
    int pos  = (int)(pv >> 12) + (int)rank[e];
    int degd = (int)(pv & 4095u);
    unsigned sp = packed_src[s >> 1];
    int degs = (int)((sp >> ((s & 1) << 4)) & 0xffffu);
    float coef = rsqrtf((float)max(degs, 1)) * rsqrtf((float)max(degd, 1));
    edges4[pos] = make_int4(s, __float_as_int(coef), d, 0);
}

// ---------------- edge-parallel segmented aggregate (R10/R11-verified) -------
// One wave per 64 consecutive dst-sorted edges: perfect load balance. Runs
// found via ballot; interior runs -> plain float4 store (sole writer);
// window-boundary runs -> atomicAdd (out pre-zeroed). No per-node state.
__global__ void aggregate_seg_kernel(const float* __restrict__ feat,
                                     const int4* __restrict__ edges4,
                                     float* __restrict__ out, int E) {
    const int lane = threadIdx.x & 63;
    const int g = lane >> 4, q = lane & 15;
    const int win = blockIdx.x * (blockDim.x >> 6) + (threadIdx.x >> 6);
    int e = (win << 6) + lane;
    if ((win << 6) >= E) return;
    int4 ed = (e < E) ? edges4[e] : make_int4(0, 0, -1, 0);
    int   d_l = ed.z, s_l = ed.x;
    float c_l = __int_as_float(ed.y);
    int d_prev = __shfl_up(d_l, 1);
    bool newrun = (lane == 0) || (d_l != d_prev);
    unsigned long long bmask = __ballot(newrun);
    int a = 0;
    while (a < 64) {
        unsigned long long rest = (a < 63) ? ((bmask >> (a + 1)) << (a + 1)) : 0ull;
        int bb = rest ? (int)__builtin_ctzll(rest) : 64;
        int dcur = __shfl(d_l, a);
        if (dcur >= 0) {
            float4 acc = make_float4(0.f, 0.f, 0.f, 0.f);
            int n4 = (bb - a + 3) >> 2;
            for (int t4 = 0; t4 < n4; ++t4) {
                int p = a + t4 * 4 + g;
                int   sj = __shfl(s_l, p & 63);
                float cj = __shfl(c_l, p & 63);
                if (p >= bb) cj = 0.f;         // inactive slot: row load harmless
                const float4 row = *(const float4*)(feat + (size_t)sj * D_FEAT + (q << 2));
                acc.x += row.x * cj; acc.y += row.y * cj;
                acc.z += row.z * cj; acc.w += row.w * cj;
            }
            #pragma unroll
            for (int m = 16; m <= 32; m <<= 1) {
                acc.x += __shfl_xor(acc.x, m); acc.y += __shfl_xor(acc.y, m);
                acc.z += __shfl_xor(acc.z, m); acc.w += __shfl_xor(acc.w, m);
            }
            bool bnd = (a == 0) || (bb == 64); // run may continue in adjacent window
            if (g == 0) {
                float* o = out + (size_t)dcur * D_FEAT + (q << 2);
                if (bnd) {
                    atomicAdd(o + 0, acc.x); atomicAdd(o + 1, acc.y);
                    atomicAdd(o + 2, acc.z); atomicAdd(o + 3, acc.w);
                } else {
                    *(float4*)o = acc;
                }
            }
        }
        a = bb;
    }
}

extern "C" void kernel_launch(void* const* d_in, const int* in_sizes, int n_in,
                              void* d_out, int out_size, void* d_ws, size_t ws_size,
                              hipStream_t stream) {
    const float* feat = (const float*)d_in[0];
    const int*   src  = (const int*)d_in[1];
    const int*   dst  = (const int*)d_in[2];
    float* out = (float*)d_out;

    const int E = in_sizes[1];
    const int N = in_sizes[0] / D_FEAT;

    // ws layout (ints): [zeroed] packed_src(65536) deg_dst(N) agg(128) incl(128)
    //                   [no init] packed_rs(N) rank(E u16) edges4(E int4, aligned)
    unsigned* packed_src = (unsigned*)d_ws;
    int* deg_dst = (int*)(packed_src + 65536);
    int* agg  = deg_dst + N;
    int* incl = agg + 128;
    unsigned* packed_rs = (unsigned*)(incl + 128);
    unsigned short* rank = (unsigned short*)(packed_rs + N);
    size_t off_ints = 65536 + (size_t)N + 256 + (size_t)N + (size_t)(E + 1) / 2;
    off_ints = (off_ints + 3) & ~(size_t)3;        // 16B align
    int4* edges4 = (int4*)((int*)d_ws + off_ints);
    (void)ws_size;

    const int zeroA_ints = 65536 + N + 256;
    const int zeroA_i4   = (zeroA_ints + 3) / 4;   // <=3-int spill into packed_rs
                                                   // (fully rewritten by scan)
    const int out_i4 = (N * D_FEAT) / 4;

    zero_kernel<<<(zeroA_i4 + out_i4 + 255) / 256, 256, 0, stream>>>(
        (int4*)d_ws, zeroA_i4, (int4*)out, out_i4);

    dst_rank_kernel<<<(E / 4 + 255) / 256, 256, 0, stream>>>(dst, deg_dst, rank, E);

    const int nscan = (N + SCAN_THR - 1) / SCAN_THR;          // 98
    scan_hist_kernel<<<nscan + HIST_RANGES * HIST_CHUNKS, SCAN_THR, 0, stream>>>(
        deg_dst, packed_rs, agg, incl, src, packed_src, N, E, nscan);

    place_kernel<<<(E + 255) / 256, 256, 0, stream>>>(src, dst, rank, packed_rs,
                                                      packed_src, edges4, E);

    const int nwin = (E + 63) / 64;                           // one wave per window
    aggregate_seg_kernel<<<(nwin + 3) / 4, 256, 0, stream>>>(feat, edges4, out, E);
}